// Round 1
// baseline (727.955 us; speedup 1.0000x reference)
//
#include <hip/hip_runtime.h>

// LocallyConnected3DFlipout:
//   out[b,p,f] = sum_k patch[b,p,k]*loc[p,k,f]
//              + sign_out[b,p,f]*sum_k (x*sign_in)patch[b,p,k]*(softplus(rho)*eps)[p,k,f]
//              + bias[f]
// patch k = c*27 + (kd*9+kh*3+kw)  (channel slowest, spatial row-major fastest).
//
// R8 = R7 with the residency premise actually enforced. R7 measured VGPR=124,
// which caps at 4 waves/SIMD -> only 1024/1280 blocks resident + 2nd dispatch
// round + 92 dual FULL tiles as tail. Counters: VALUBusy 29%, HBM 16%,
// Occupancy 18% -> pure latency-bound, under-occupied.
// Changes (compute body is the verified R3 body, untouched):
//  1. PPB 16->8, THREADS 256->128 (8 pos x 16 batch-pairs). Same per-thread
//     work shape: 2 batches, 16 accumulators. LDS 28.2KB -> 14KB.
//  2. __launch_bounds__(128, 5): force VGPR <= 102 (R3 proved body fits 92)
//     -> 5 waves/SIMD -> 10 blocks/CU resident.
//  3. GRID = 2560 = exactly 10 blocks/CU, all co-resident. NT = 2744 = 8*343
//     divides EXACTLY over 8 XCDs (343 contiguous tiles each, per-XCD x/sign
//     working set ~2.8MB < 4MB L2 -> keeps R7's XCD-locality win). 184 blocks
//     (slots 0..22 per XCD, lowest blockIdx, launched first) take 2 adjacent
//     half-tiles; tail is now <= one half-tile at low contention.

constexpr int Bn   = 32;
constexpr int Dn   = 30;
constexpr int Cn   = 4;
constexpr int ODn  = 28;
constexpr int Pn   = ODn * ODn * ODn;   // 21952
constexpr int Tt   = 27;
constexpr int Kn   = Tt * Cn;           // 108
constexpr int PPB  = 8;                 // positions per tile (half of R7)
constexpr int NT   = Pn / PPB;          // 2744 tiles = 8 * 343
constexpr int THREADS = 128;            // 8 pos x 16 batch-pairs
constexpr int WSTRIDE = Kn + 1;         // 109 uint4/p (p-stride 436 dw == 20 mod 32 -> conflict-free)
constexpr int TPX  = NT / 8;            // 343 tiles per XCD (exact)
constexpr int BPX  = 320;               // blocks per XCD
constexpr int EX   = TPX - BPX;         // 23 dual-tile slots per XCD
constexpr int GRID = BPX * 8;           // 2560 = 10 blocks/CU x 256 CU

__device__ __forceinline__ unsigned bf16rne(float f) {
    unsigned u = __float_as_uint(f);
    return (u + 0x7fffu + ((u >> 16) & 1u)) >> 16;
}
__device__ __forceinline__ float bflo(unsigned u) { return __uint_as_float(u << 16); }
__device__ __forceinline__ float bfhi(unsigned u) { return __uint_as_float(u & 0xffff0000u); }

__global__ __launch_bounds__(THREADS, 5) void lc3d_flipout_kernel(
    const float* __restrict__ x,        // [B,30,30,30,4]
    const float* __restrict__ loc,      // [P,108,4]
    const float* __restrict__ rho,      // [P,108,4]
    const float* __restrict__ bias,     // [4]
    const float* __restrict__ eps,      // [P,108,4]
    const float* __restrict__ sgn_in,   // [B,30,30,30,4]
    const float* __restrict__ sgn_out,  // [B,P,4]
    float* __restrict__ out)            // [B,P,4]
{
    __shared__ uint4 wsh[PPB * WSTRIDE];   // 8*109*16 = 13,952 B

    const int tid = threadIdx.x;

    // ---- XCD-contiguous persistent tile assignment (exact 343/XCD) ----
    // Block i -> xcd i&7, slot i>>3 (320 slots/xcd). Slots 0..22 own the two
    // adjacent tiles {2s, 2s+1}; slots 23..319 own tile {s+23}. Bijective
    // onto [0,343) per XCD; dual blocks have the lowest blockIdx -> start first.
    const int xcd  = blockIdx.x & 7;
    const int slot = blockIdx.x >> 3;
    const int ntiles = (slot < EX) ? 2 : 1;
    const int t0 = xcd * TPX + ((slot < EX) ? (slot * 2) : (slot + EX));

    const float4 bi = *(const float4*)bias;

#pragma unroll 1
    for (int it = 0; it < ntiles; ++it) {
        const int p_base = (t0 + it) * PPB;
        if (it) __syncthreads();        // LDS slab reuse hazard between tiles

        // ---- Stage weights: 864 uint4; coalesced global, sequential LDS ----
        const float4* loc4 = (const float4*)loc + (size_t)p_base * Kn;
        const float4* rho4 = (const float4*)rho + (size_t)p_base * Kn;
        const float4* eps4 = (const float4*)eps + (size_t)p_base * Kn;
        for (int g = tid; g < PPB * Kn; g += THREADS) {
            const int plc = g / Kn;
            const int k   = g - plc * Kn;
            const float4 L = loc4[g];
            const float4 R = rho4[g];
            const float4 E = eps4[g];
            float nx = (R.x > 15.f ? R.x : __logf(1.f + __expf(R.x))) * E.x;
            float ny = (R.y > 15.f ? R.y : __logf(1.f + __expf(R.y))) * E.y;
            float nz = (R.z > 15.f ? R.z : __logf(1.f + __expf(R.z))) * E.z;
            float nw = (R.w > 15.f ? R.w : __logf(1.f + __expf(R.w))) * E.w;
            uint4 pk;
            pk.x = bf16rne(L.x) | (bf16rne(L.y) << 16);
            pk.y = bf16rne(L.z) | (bf16rne(L.w) << 16);
            pk.z = bf16rne(nx)  | (bf16rne(ny) << 16);
            pk.w = bf16rne(nz)  | (bf16rne(nw) << 16);
            wsh[plc * WSTRIDE + k] = pk;
        }
        __syncthreads();

        // ---- Compute (verified R3 body): lane = (bh, pl), 2 batches/thread ----
        const int pl = tid & 7;
        const int bh = tid >> 3;        // 0..15
        const int b0 = bh, b1 = bh + 16;
        const int p  = p_base + pl;
        const int od = p / (ODn * ODn);
        const int prem = p - od * (ODn * ODn);
        const int oh = prem / ODn;
        const int ow = prem - oh * ODn;
        const float4* x4 = (const float4*)x;
        const float4* s4 = (const float4*)sgn_in;
        const size_t v0 = (((size_t)b0 * Dn + od) * Dn + oh) * Dn + ow;
        const size_t v1 = (((size_t)b1 * Dn + od) * Dn + oh) * Dn + ow;
        const uint4* wp = wsh + pl * WSTRIDE;

        float a00=0.f,a01=0.f,a02=0.f,a03=0.f, a10=0.f,a11=0.f,a12=0.f,a13=0.f;
        float n00=0.f,n01=0.f,n02=0.f,n03=0.f, n10=0.f,n11=0.f,n12=0.f,n13=0.f;

#define CHAN(c, xa_c, sa_c, xb_c, sb_c)                                      \
        {                                                                    \
            const uint4 wv = wp[(c) * Tt + t];                               \
            const float m0 = bflo(wv.x), m1 = bfhi(wv.x);                    \
            const float m2 = bflo(wv.y), m3 = bfhi(wv.y);                    \
            const float q0 = bflo(wv.z), q1 = bfhi(wv.z);                    \
            const float q2 = bflo(wv.w), q3 = bfhi(wv.w);                    \
            a00 = fmaf(xa_c, m0, a00); a01 = fmaf(xa_c, m1, a01);            \
            a02 = fmaf(xa_c, m2, a02); a03 = fmaf(xa_c, m3, a03);            \
            a10 = fmaf(xb_c, m0, a10); a11 = fmaf(xb_c, m1, a11);            \
            a12 = fmaf(xb_c, m2, a12); a13 = fmaf(xb_c, m3, a13);            \
            const float ya = (xa_c) * (sa_c);                                \
            const float yb = (xb_c) * (sb_c);                                \
            n00 = fmaf(ya, q0, n00); n01 = fmaf(ya, q1, n01);                \
            n02 = fmaf(ya, q2, n02); n03 = fmaf(ya, q3, n03);                \
            n10 = fmaf(yb, q0, n10); n11 = fmaf(yb, q1, n11);                \
            n12 = fmaf(yb, q2, n12); n13 = fmaf(yb, q3, n13);                \
        }

        #pragma unroll
        for (int kd = 0; kd < 3; ++kd) {
            #pragma unroll
            for (int kh = 0; kh < 3; ++kh) {
                const int roff = (kd * Dn + kh) * Dn;
                #pragma unroll
                for (int kw = 0; kw < 3; ++kw) {
                    const int t = (kd * 3 + kh) * 3 + kw;
                    const float4 xa = x4[v0 + roff + kw];
                    const float4 sa = s4[v0 + roff + kw];
                    const float4 xb = x4[v1 + roff + kw];
                    const float4 sb = s4[v1 + roff + kw];
                    CHAN(0, xa.x, sa.x, xb.x, sb.x);
                    CHAN(1, xa.y, sa.y, xb.y, sb.y);
                    CHAN(2, xa.z, sa.z, xb.z, sb.z);
                    CHAN(3, xa.w, sa.w, xb.w, sb.w);
                }
            }
        }
#undef CHAN

        // ---- Epilogue: coalesced (8 consecutive p per bh-group) ----
        const size_t ob0 = (size_t)b0 * Pn + p;
        const size_t ob1 = (size_t)b1 * Pn + p;
        const float4 so0 = ((const float4*)sgn_out)[ob0];
        const float4 so1 = ((const float4*)sgn_out)[ob1];
        float4 o0, o1;
        o0.x = fmaf(so0.x, n00, a00) + bi.x;
        o0.y = fmaf(so0.y, n01, a01) + bi.y;
        o0.z = fmaf(so0.z, n02, a02) + bi.z;
        o0.w = fmaf(so0.w, n03, a03) + bi.w;
        o1.x = fmaf(so1.x, n10, a10) + bi.x;
        o1.y = fmaf(so1.y, n11, a11) + bi.y;
        o1.z = fmaf(so1.z, n12, a12) + bi.z;
        o1.w = fmaf(so1.w, n13, a13) + bi.w;
        ((float4*)out)[ob0] = o0;
        ((float4*)out)[ob1] = o1;
    }
}

extern "C" void kernel_launch(void* const* d_in, const int* in_sizes, int n_in,
                              void* d_out, int out_size, void* d_ws, size_t ws_size,
                              hipStream_t stream) {
    const float* x    = (const float*)d_in[0];
    const float* loc  = (const float*)d_in[1];
    const float* rho  = (const float*)d_in[2];
    const float* bias = (const float*)d_in[3];
    const float* eps  = (const float*)d_in[4];
    const float* si   = (const float*)d_in[5];
    const float* so   = (const float*)d_in[6];
    float* out = (float*)d_out;

    lc3d_flipout_kernel<<<dim3(GRID), dim3(THREADS), 0, stream>>>(
        x, loc, rho, bias, eps, si, so, out);
}

// Round 2
// 212.331 us; speedup vs baseline: 3.4284x; 3.4284x over previous
//
#include <hip/hip_runtime.h>

// LocallyConnected3DFlipout:
//   out[b,p,f] = sum_k patch[b,p,k]*loc[p,k,f]
//              + sign_out[b,p,f]*sum_k (x*sign_in)patch[b,p,k]*(softplus(rho)*eps)[p,k,f]
//              + bias[f]
// patch k = c*27 + (kd*9+kh*3+kw)  (channel slowest, spatial row-major fastest).
//
// R9 = R3's flat structure (single tile per block, natural 92-VGPR body,
// NO launch_bounds min-waves arg) + R7's XCD-contiguous tile remap only.
// History:
//  - R7 (84.6us): persistent 2-tile loop grew VGPR to 124 -> 4 waves/SIMD
//    (tier boundary is 102); occupancy 18%, VALUBusy 29% -> latency-bound.
//  - R8: __launch_bounds__(128,5) clamped VGPR to 48 < body's ~92 ->
//    catastrophic scratch spill (1.46 GB writes, 620us). NEVER force the
//    allocator below ~92 for this body.
//  - R9 removes the persistent loop (the source of R7's VGPR growth) so the
//    allocator lands back at R3's ~92 -> 5 waves/SIMD -> 5 blocks/CU
//    (LDS 28KB -> 160/28 = 5.7 blocks, not binding). Keeps the XCD-contiguous
//    mapping (per-XCD x/sign_in working set ~2.9MB < 4MB L2) that made R7
//    faster than R3. Tail: 92 of 1372 blocks queue behind the 1280 resident;
//    staggered finish -> ~one tile of tail, same as R7's dual-tile tail.

constexpr int Bn   = 32;
constexpr int Dn   = 30;
constexpr int Cn   = 4;
constexpr int ODn  = 28;
constexpr int Pn   = ODn * ODn * ODn;   // 21952
constexpr int Tt   = 27;
constexpr int Kn   = Tt * Cn;           // 108
constexpr int PPB  = 16;                // positions per tile
constexpr int NT   = Pn / PPB;          // 1372 tiles
constexpr int THREADS = 256;
constexpr int WSTRIDE = Kn + 1;         // 109 uint4/p (p-stride 436 dw == 20 mod 32 -> 2-way max, free)
constexpr int GRID = NT;                // 1372 single-tile blocks

__device__ __forceinline__ unsigned bf16rne(float f) {
    unsigned u = __float_as_uint(f);
    return (u + 0x7fffu + ((u >> 16) & 1u)) >> 16;
}
__device__ __forceinline__ float bflo(unsigned u) { return __uint_as_float(u << 16); }
__device__ __forceinline__ float bfhi(unsigned u) { return __uint_as_float(u & 0xffff0000u); }

__global__ __launch_bounds__(THREADS) void lc3d_flipout_kernel(
    const float* __restrict__ x,        // [B,30,30,30,4]
    const float* __restrict__ loc,      // [P,108,4]
    const float* __restrict__ rho,      // [P,108,4]
    const float* __restrict__ bias,     // [4]
    const float* __restrict__ eps,      // [P,108,4]
    const float* __restrict__ sgn_in,   // [B,30,30,30,4]
    const float* __restrict__ sgn_out,  // [B,P,4]
    float* __restrict__ out)            // [B,P,4]
{
    __shared__ uint4 wsh[PPB * WSTRIDE];   // 16*109*16 = 27,904 B

    const int tid = threadIdx.x;

    // ---- XCD-contiguous tile remap (assumes dispatch: block i -> XCD i%8) ----
    // 1372 tiles over 8 XCDs: first 4 XCDs own 172 contiguous tiles, last 4
    // own 171. Block i -> xcd i&7, slot i>>3. Bijective: xcd<4 sees slots
    // 0..171 (172), xcd>=4 sees slots 0..170 (171); 4*172+4*171 = 1372.
    const int xcd  = blockIdx.x & 7;
    const int slot = blockIdx.x >> 3;
    const int Tx = (xcd < 4) ? xcd * 172 : 688 + (xcd - 4) * 171;
    const int p_base = (Tx + slot) * PPB;

    // ---- Stage weights: 1728 uint4; coalesced global, sequential LDS ----
    const float4* loc4 = (const float4*)loc + (size_t)p_base * Kn;
    const float4* rho4 = (const float4*)rho + (size_t)p_base * Kn;
    const float4* eps4 = (const float4*)eps + (size_t)p_base * Kn;
    for (int g = tid; g < PPB * Kn; g += THREADS) {
        const int plc = g / Kn;
        const int k   = g - plc * Kn;
        const float4 L = loc4[g];
        const float4 R = rho4[g];
        const float4 E = eps4[g];
        float nx = (R.x > 15.f ? R.x : __logf(1.f + __expf(R.x))) * E.x;
        float ny = (R.y > 15.f ? R.y : __logf(1.f + __expf(R.y))) * E.y;
        float nz = (R.z > 15.f ? R.z : __logf(1.f + __expf(R.z))) * E.z;
        float nw = (R.w > 15.f ? R.w : __logf(1.f + __expf(R.w))) * E.w;
        uint4 pk;
        pk.x = bf16rne(L.x) | (bf16rne(L.y) << 16);
        pk.y = bf16rne(L.z) | (bf16rne(L.w) << 16);
        pk.z = bf16rne(nx)  | (bf16rne(ny) << 16);
        pk.w = bf16rne(nz)  | (bf16rne(nw) << 16);
        wsh[plc * WSTRIDE + k] = pk;
    }
    __syncthreads();

    // ---- Compute (verified R3 body): lane = (bh, pl), 2 batches/thread ----
    const int pl = tid & 15;
    const int bh = tid >> 4;
    const int b0 = bh, b1 = bh + 16;
    const int p  = p_base + pl;
    const int od = p / (ODn * ODn);
    const int prem = p - od * (ODn * ODn);
    const int oh = prem / ODn;
    const int ow = prem - oh * ODn;
    const float4* x4 = (const float4*)x;
    const float4* s4 = (const float4*)sgn_in;
    const size_t v0 = (((size_t)b0 * Dn + od) * Dn + oh) * Dn + ow;
    const size_t v1 = (((size_t)b1 * Dn + od) * Dn + oh) * Dn + ow;
    const uint4* wp = wsh + pl * WSTRIDE;

    float a00=0.f,a01=0.f,a02=0.f,a03=0.f, a10=0.f,a11=0.f,a12=0.f,a13=0.f;
    float n00=0.f,n01=0.f,n02=0.f,n03=0.f, n10=0.f,n11=0.f,n12=0.f,n13=0.f;

#define CHAN(c, xa_c, sa_c, xb_c, sb_c)                                      \
    {                                                                        \
        const uint4 wv = wp[(c) * Tt + t];                                   \
        const float m0 = bflo(wv.x), m1 = bfhi(wv.x);                        \
        const float m2 = bflo(wv.y), m3 = bfhi(wv.y);                        \
        const float q0 = bflo(wv.z), q1 = bfhi(wv.z);                        \
        const float q2 = bflo(wv.w), q3 = bfhi(wv.w);                        \
        a00 = fmaf(xa_c, m0, a00); a01 = fmaf(xa_c, m1, a01);                \
        a02 = fmaf(xa_c, m2, a02); a03 = fmaf(xa_c, m3, a03);                \
        a10 = fmaf(xb_c, m0, a10); a11 = fmaf(xb_c, m1, a11);                \
        a12 = fmaf(xb_c, m2, a12); a13 = fmaf(xb_c, m3, a13);                \
        const float ya = (xa_c) * (sa_c);                                    \
        const float yb = (xb_c) * (sb_c);                                    \
        n00 = fmaf(ya, q0, n00); n01 = fmaf(ya, q1, n01);                    \
        n02 = fmaf(ya, q2, n02); n03 = fmaf(ya, q3, n03);                    \
        n10 = fmaf(yb, q0, n10); n11 = fmaf(yb, q1, n11);                    \
        n12 = fmaf(yb, q2, n12); n13 = fmaf(yb, q3, n13);                    \
    }

    #pragma unroll
    for (int kd = 0; kd < 3; ++kd) {
        #pragma unroll
        for (int kh = 0; kh < 3; ++kh) {
            const int roff = (kd * Dn + kh) * Dn;
            #pragma unroll
            for (int kw = 0; kw < 3; ++kw) {
                const int t = (kd * 3 + kh) * 3 + kw;
                const float4 xa = x4[v0 + roff + kw];
                const float4 sa = s4[v0 + roff + kw];
                const float4 xb = x4[v1 + roff + kw];
                const float4 sb = s4[v1 + roff + kw];
                CHAN(0, xa.x, sa.x, xb.x, sb.x);
                CHAN(1, xa.y, sa.y, xb.y, sb.y);
                CHAN(2, xa.z, sa.z, xb.z, sb.z);
                CHAN(3, xa.w, sa.w, xb.w, sb.w);
            }
        }
    }
#undef CHAN

    // ---- Epilogue: coalesced (16 consecutive p per cluster) ----
    const float4 bi = *(const float4*)bias;
    const size_t ob0 = (size_t)b0 * Pn + p;
    const size_t ob1 = (size_t)b1 * Pn + p;
    const float4 so0 = ((const float4*)sgn_out)[ob0];
    const float4 so1 = ((const float4*)sgn_out)[ob1];
    float4 o0, o1;
    o0.x = fmaf(so0.x, n00, a00) + bi.x;
    o0.y = fmaf(so0.y, n01, a01) + bi.y;
    o0.z = fmaf(so0.z, n02, a02) + bi.z;
    o0.w = fmaf(so0.w, n03, a03) + bi.w;
    o1.x = fmaf(so1.x, n10, a10) + bi.x;
    o1.y = fmaf(so1.y, n11, a11) + bi.y;
    o1.z = fmaf(so1.z, n12, a12) + bi.z;
    o1.w = fmaf(so1.w, n13, a13) + bi.w;
    ((float4*)out)[ob0] = o0;
    ((float4*)out)[ob1] = o1;
}

extern "C" void kernel_launch(void* const* d_in, const int* in_sizes, int n_in,
                              void* d_out, int out_size, void* d_ws, size_t ws_size,
                              hipStream_t stream) {
    const float* x    = (const float*)d_in[0];
    const float* loc  = (const float*)d_in[1];
    const float* rho  = (const float*)d_in[2];
    const float* bias = (const float*)d_in[3];
    const float* eps  = (const float*)d_in[4];
    const float* si   = (const float*)d_in[5];
    const float* so   = (const float*)d_in[6];
    float* out = (float*)d_out;

    lc3d_flipout_kernel<<<dim3(GRID), dim3(THREADS), 0, stream>>>(
        x, loc, rho, bias, eps, si, so, out);
}

// Round 3
// 206.099 us; speedup vs baseline: 3.5321x; 1.0302x over previous
//
#include <hip/hip_runtime.h>

// LocallyConnected3DFlipout:
//   out[b,p,f] = sum_k patch[b,p,k]*loc[p,k,f]
//              + sign_out[b,p,f]*sum_k (x*sign_in)patch[b,p,k]*(softplus(rho)*eps)[p,k,f]
//              + bias[f]
// patch k = c*27 + (kd*9+kh*3+kw)  (channel slowest, spatial row-major fastest).
//
// R10: more, lighter waves. R7/R9 post-mortem: VGPR tier (124 vs 92) changed
// NOTHING — OccupancyPercent pinned at 18.5%, VALUBusy ~26%, HBM ~15% in both.
// Phase-serialized latency-bound. The untried axis is wave count per CU:
//  - 1 batch/thread (8 accumulators, not 16), 512-thread blocks (16 pos x 32
//    batch). Natural VGPR target ~60-72 -> 7-8 waves/SIMD (no launch_bounds
//    forcing — R8 proved clamping = catastrophic spill). 28-32 waves/CU vs 20.
//  - Per-wave instruction stream halves -> half the latency exposure per wave.
//  - Stage loads hand-hoisted: 3 uniform rounds (1728 = 3*512 + 192 tail),
//    all 9 float4 loads issued before any softplus -> whole 83KB weight tile
//    in flight at once instead of 3-4 serialized ~900cy HBM rounds.
//  - Keeps R7/R9's XCD-contiguous tile remap (per-XCD x/sign working set
//    ~2.9MB < 4MB L2).
// Accepted costs: total LDS-read instrs double (floor ~23us, far under the
// 93us measured), unpack VALU per FMA +18%. Output accumulation order per
// element is unchanged -> absmax identical to R9.

constexpr int Bn   = 32;
constexpr int Dn   = 30;
constexpr int Cn   = 4;
constexpr int ODn  = 28;
constexpr int Pn   = ODn * ODn * ODn;   // 21952
constexpr int Tt   = 27;
constexpr int Kn   = Tt * Cn;           // 108
constexpr int PPB  = 16;                // positions per tile
constexpr int NT   = Pn / PPB;          // 1372 tiles
constexpr int THREADS = 512;            // 16 pos x 32 batches, 1 batch/thread
constexpr int WSTRIDE = Kn + 1;         // 109 uint4/p (p-stride 436 dw == 20 mod 32 -> 2-way max, free)
constexpr int GRID = NT;                // 1372 single-tile blocks

__device__ __forceinline__ unsigned bf16rne(float f) {
    unsigned u = __float_as_uint(f);
    return (u + 0x7fffu + ((u >> 16) & 1u)) >> 16;
}
__device__ __forceinline__ float bflo(unsigned u) { return __uint_as_float(u << 16); }
__device__ __forceinline__ float bfhi(unsigned u) { return __uint_as_float(u & 0xffff0000u); }

__device__ __forceinline__ uint4 pack_w(const float4 L, const float4 R, const float4 E) {
    float nx = (R.x > 15.f ? R.x : __logf(1.f + __expf(R.x))) * E.x;
    float ny = (R.y > 15.f ? R.y : __logf(1.f + __expf(R.y))) * E.y;
    float nz = (R.z > 15.f ? R.z : __logf(1.f + __expf(R.z))) * E.z;
    float nw = (R.w > 15.f ? R.w : __logf(1.f + __expf(R.w))) * E.w;
    uint4 pk;
    pk.x = bf16rne(L.x) | (bf16rne(L.y) << 16);
    pk.y = bf16rne(L.z) | (bf16rne(L.w) << 16);
    pk.z = bf16rne(nx)  | (bf16rne(ny) << 16);
    pk.w = bf16rne(nz)  | (bf16rne(nw) << 16);
    return pk;
}

__global__ __launch_bounds__(THREADS) void lc3d_flipout_kernel(
    const float* __restrict__ x,        // [B,30,30,30,4]
    const float* __restrict__ loc,      // [P,108,4]
    const float* __restrict__ rho,      // [P,108,4]
    const float* __restrict__ bias,     // [4]
    const float* __restrict__ eps,      // [P,108,4]
    const float* __restrict__ sgn_in,   // [B,30,30,30,4]
    const float* __restrict__ sgn_out,  // [B,P,4]
    float* __restrict__ out)            // [B,P,4]
{
    __shared__ uint4 wsh[PPB * WSTRIDE];   // 16*109*16 = 27,904 B

    const int tid = threadIdx.x;

    // ---- XCD-contiguous tile remap (assumes dispatch: block i -> XCD i%8) ----
    // 1372 tiles over 8 XCDs: first 4 XCDs own 172 contiguous tiles, last 4
    // own 171. Block i -> xcd i&7, slot i>>3. Bijective.
    const int xcd  = blockIdx.x & 7;
    const int slot = blockIdx.x >> 3;
    const int Tx = (xcd < 4) ? xcd * 172 : 688 + (xcd - 4) * 171;
    const int p_base = (Tx + slot) * PPB;

    // ---- Stage weights: 1728 uint4 = 3*512 + 192. Loads hoisted: all nine
    // float4 loads in flight before any softplus -> one HBM latency, not 3-4.
    {
        const float4* loc4 = (const float4*)loc + (size_t)p_base * Kn;
        const float4* rho4 = (const float4*)rho + (size_t)p_base * Kn;
        const float4* eps4 = (const float4*)eps + (size_t)p_base * Kn;
        const int g0 = tid, g1 = tid + 512, g2 = tid + 1024;
        const float4 L0 = loc4[g0], R0 = rho4[g0], E0 = eps4[g0];
        const float4 L1 = loc4[g1], R1 = rho4[g1], E1 = eps4[g1];
        const float4 L2 = loc4[g2], R2 = rho4[g2], E2 = eps4[g2];
        {
            const int plc = g0 / Kn, k = g0 - plc * Kn;
            wsh[plc * WSTRIDE + k] = pack_w(L0, R0, E0);
        }
        {
            const int plc = g1 / Kn, k = g1 - plc * Kn;
            wsh[plc * WSTRIDE + k] = pack_w(L1, R1, E1);
        }
        {
            const int plc = g2 / Kn, k = g2 - plc * Kn;
            wsh[plc * WSTRIDE + k] = pack_w(L2, R2, E2);
        }
        if (tid < PPB * Kn - 1536) {
            const int g3 = tid + 1536;
            const int plc = g3 / Kn, k = g3 - plc * Kn;
            wsh[plc * WSTRIDE + k] = pack_w(loc4[g3], rho4[g3], eps4[g3]);
        }
    }
    __syncthreads();

    // ---- Compute: lane = (b, pl), ONE batch per thread, 8 accumulators ----
    const int pl = tid & 15;
    const int b  = tid >> 4;            // 0..31
    const int p  = p_base + pl;
    const int od = p / (ODn * ODn);
    const int prem = p - od * (ODn * ODn);
    const int oh = prem / ODn;
    const int ow = prem - oh * ODn;
    const float4* x4 = (const float4*)x;
    const float4* s4 = (const float4*)sgn_in;
    const size_t v0 = (((size_t)b * Dn + od) * Dn + oh) * Dn + ow;
    const uint4* wp = wsh + pl * WSTRIDE;

    float a0=0.f,a1=0.f,a2=0.f,a3=0.f, n0=0.f,n1=0.f,n2=0.f,n3=0.f;

#define CHAN(c, x_c, s_c)                                                    \
    {                                                                        \
        const uint4 wv = wp[(c) * Tt + t];                                   \
        const float m0 = bflo(wv.x), m1 = bfhi(wv.x);                        \
        const float m2 = bflo(wv.y), m3 = bfhi(wv.y);                        \
        const float q0 = bflo(wv.z), q1 = bfhi(wv.z);                        \
        const float q2 = bflo(wv.w), q3 = bfhi(wv.w);                        \
        a0 = fmaf(x_c, m0, a0); a1 = fmaf(x_c, m1, a1);                      \
        a2 = fmaf(x_c, m2, a2); a3 = fmaf(x_c, m3, a3);                      \
        const float ya = (x_c) * (s_c);                                      \
        n0 = fmaf(ya, q0, n0); n1 = fmaf(ya, q1, n1);                        \
        n2 = fmaf(ya, q2, n2); n3 = fmaf(ya, q3, n3);                        \
    }

    #pragma unroll
    for (int kd = 0; kd < 3; ++kd) {
        #pragma unroll
        for (int kh = 0; kh < 3; ++kh) {
            const int roff = (kd * Dn + kh) * Dn;
            #pragma unroll
            for (int kw = 0; kw < 3; ++kw) {
                const int t = (kd * 3 + kh) * 3 + kw;
                const float4 xa = x4[v0 + roff + kw];
                const float4 sa = s4[v0 + roff + kw];
                CHAN(0, xa.x, sa.x);
                CHAN(1, xa.y, sa.y);
                CHAN(2, xa.z, sa.z);
                CHAN(3, xa.w, sa.w);
            }
        }
    }
#undef CHAN

    // ---- Epilogue: coalesced (16 consecutive p per b-group) ----
    const float4 bi = *(const float4*)bias;
    const size_t ob = (size_t)b * Pn + p;
    const float4 so = ((const float4*)sgn_out)[ob];
    float4 o;
    o.x = fmaf(so.x, n0, a0) + bi.x;
    o.y = fmaf(so.y, n1, a1) + bi.y;
    o.z = fmaf(so.z, n2, a2) + bi.z;
    o.w = fmaf(so.w, n3, a3) + bi.w;
    ((float4*)out)[ob] = o;
}

extern "C" void kernel_launch(void* const* d_in, const int* in_sizes, int n_in,
                              void* d_out, int out_size, void* d_ws, size_t ws_size,
                              hipStream_t stream) {
    const float* x    = (const float*)d_in[0];
    const float* loc  = (const float*)d_in[1];
    const float* rho  = (const float*)d_in[2];
    const float* bias = (const float*)d_in[3];
    const float* eps  = (const float*)d_in[4];
    const float* si   = (const float*)d_in[5];
    const float* so   = (const float*)d_in[6];
    float* out = (float*)d_out;

    lc3d_flipout_kernel<<<dim3(GRID), dim3(THREADS), 0, stream>>>(
        x, loc, rho, bias, eps, si, so, out);
}